// Round 4
// baseline (189.459 us; speedup 1.0000x reference)
//
#include <hip/hip_runtime.h>
#include <stdint.h>

#define SQ 2048
#define DH 128
#define SCALER 0.08838834764831845f  // 1/sqrt(128)

typedef float f32x4 __attribute__((ext_vector_type(4)));
typedef short s16x8 __attribute__((ext_vector_type(8)));

__device__ __forceinline__ short f2bf(float f) {
  uint32_t x = __float_as_uint(f);
  uint32_t r = (x + 0x7fffu + ((x >> 16) & 1u)) >> 16;  // RNE
  return (short)(r & 0xffffu);
}

__device__ __forceinline__ void mfma16(f32x4& d, s16x8 a, s16x8 b) {
  asm("v_mfma_f32_16x16x32_bf16 %0, %1, %2, %0" : "+v"(d) : "v"(a), "v"(b));
}

__device__ __forceinline__ void gload16(const void* g, void* l) {
  __builtin_amdgcn_global_load_lds(
      (__attribute__((address_space(1))) void*)const_cast<void*>(g),
      (__attribute__((address_space(3))) void*)l, 16, 0, 0);
}

// ---------------- f32 -> bf16 convert (linear layout) ----------------
__global__ __launch_bounds__(256) void cvt_bf16(const float* __restrict__ in,
                                                short* __restrict__ out, int n8) {
  int i = blockIdx.x * 256 + threadIdx.x;
  if (i >= n8) return;
  const float4* p = (const float4*)in + (size_t)i * 2;
  float4 a = p[0], b = p[1];
  s16x8 o;
  o[0] = f2bf(a.x); o[1] = f2bf(a.y); o[2] = f2bf(a.z); o[3] = f2bf(a.w);
  o[4] = f2bf(b.x); o[5] = f2bf(b.y); o[6] = f2bf(b.z); o[7] = f2bf(b.w);
  *((s16x8*)out + i) = o;
}

// ---------------- GEMM: C[M][N] = A[M][K] * B[N][K]^T + bias ----------------
// MODE 0: plain f32 C write.
// MODE 1: fused RoPE+split epilogue -> qws/kws/vtws bf16 (QKV projection).
template <int MODE>
__global__ __launch_bounds__(256) void gemm_bt_bias(
    const short* __restrict__ A, const short* __restrict__ B,
    const float* __restrict__ bias, float* __restrict__ C,
    const float* __restrict__ pe, short* __restrict__ qws,
    short* __restrict__ kws, short* __restrict__ vtws,
    int M, int N, int K) {
  __shared__ __align__(16) short As[128 * 64];
  __shared__ __align__(16) short Bs[128 * 64];
  const int t = threadIdx.x;
  const int l = t & 63, w = t >> 6;
  const int wr = w >> 1, wc = w & 1;
  const int lr = l & 15, lk = l >> 4;
  const int m0 = blockIdx.y * 128, n0 = blockIdx.x * 128;

  f32x4 acc[4][4] = {};

  for (int kt = 0; kt < K; kt += 64) {
    const short* ga = A + (size_t)m0 * K + kt;
    const short* gb = B + (size_t)n0 * K + kt;
#pragma unroll
    for (int i = 0; i < 4; ++i) {
      int j = i * 256 + t;                       // 16B chunk id, 0..1023
      int lbase = (i * 256 + (t & ~63)) << 4;    // wave-uniform LDS byte base
      gload16(ga + (size_t)(j >> 3) * K + ((j & 7) << 3), (char*)As + lbase);
      gload16(gb + (size_t)(j >> 3) * K + ((j & 7) << 3), (char*)Bs + lbase);
    }
    __syncthreads();
#pragma unroll
    for (int ks = 0; ks < 2; ++ks) {
      s16x8 af[4], bg[4];
#pragma unroll
      for (int i = 0; i < 4; ++i) {
        af[i] = *(const s16x8*)(As + (wr * 64 + i * 16 + lr) * 64 + ks * 32 + lk * 8);
        bg[i] = *(const s16x8*)(Bs + (wc * 64 + i * 16 + lr) * 64 + ks * 32 + lk * 8);
      }
#pragma unroll
      for (int mi = 0; mi < 4; ++mi)
#pragma unroll
        for (int ni = 0; ni < 4; ++ni)
          mfma16(acc[mi][ni], af[mi], bg[ni]);
    }
    __syncthreads();
  }

#pragma unroll
  for (int mi = 0; mi < 4; ++mi) {
    int row = m0 + wr * 64 + mi * 16 + lk * 4;
#pragma unroll
    for (int ni = 0; ni < 4; ++ni) {
      int col = n0 + wc * 64 + ni * 16 + lr;
      float bv = bias[col];
#pragma unroll
      for (int r = 0; r < 4; ++r) {
        float v = acc[mi][ni][r] + bv;
        if (MODE == 0) {
          C[(size_t)(row + r) * N + col] = v;
        } else {
          int s = row + r;
          int d = col & 127;
          if (n0 < 2048) {         // Q heads: rope + scale
            float p = __shfl_xor(v, 1);
            const float* per = pe + (size_t)s * 256;
            float y = (v * per[d] + p * per[128 + d]) * SCALER;
            int hq = col >> 7;
            qws[((size_t)hq * SQ + s) * DH + d] = f2bf(y);
          } else if (n0 < 2304) {  // K heads: rope + swizzled store
            float p = __shfl_xor(v, 1);
            const float* per = pe + (size_t)s * 256;
            float y = v * per[d] + p * per[128 + d];
            int hk = (col - 2048) >> 7;
            kws[(size_t)hk * SQ * DH + (size_t)s * DH +
                (size_t)((((d >> 3) ^ (s & 15)) << 3) + (d & 7))] = f2bf(y);
          } else {                 // V heads: transposed + swizzled store
            int hk = (col - 2304) >> 7;
            int sl = s & 63;
            vtws[(size_t)hk * DH * SQ + (size_t)d * SQ + (s >> 6) * 64 +
                 (size_t)((((sl >> 3) ^ (d & 7)) << 3) + (sl & 7))] = f2bf(v);
          }
        }
      }
    }
  }
}

// ---------------- Flash attention ----------------
// 512 WGs: (h, qb). 4 waves x 16 q-rows (QBLK=64). KBLK=64, double-buffered.
// qb mapping balances co-resident pairs (bx, bx+256): iteration sums == 33.
__global__ __launch_bounds__(256) void attn_fwd(
    const short* __restrict__ qws, const short* __restrict__ kws,
    const short* __restrict__ vtws, short* __restrict__ attnws) {
  __shared__ __align__(16) short Ks[2][64 * 128];  // [buf][krow][d], slots swizzled
  __shared__ __align__(16) short Vt[2][128 * 64];  // [buf][d][kcol], slots swizzled
  __shared__ __align__(16) short Ps[4][16 * 72];   // per-wave P, row pad 72

  const int bx = blockIdx.x;
  const int h = bx & 15;
  const int i_ = bx >> 4;
  const int qb = (i_ < 16) ? (31 - i_) : (i_ - 16);  // balanced pairing
  const int hk = h >> 3;
  const int t = threadIdx.x, l = t & 63, w = t >> 6;
  const int lr = l & 15, lk = l >> 4;

  // Q fragments (rows qb*64 + w*16 + lr)
  s16x8 qf[4];
  {
    const short* qbase = qws + ((size_t)h * SQ + (size_t)qb * 64 + w * 16) * DH;
#pragma unroll
    for (int kd = 0; kd < 4; ++kd)
      qf[kd] = *(const s16x8*)(qbase + (size_t)lr * DH + kd * 32 + lk * 8);
  }

  f32x4 o[8] = {};
  f32x4 m_, l_;
#pragma unroll
  for (int r = 0; r < 4; ++r) { m_[r] = -1e30f; l_[r] = 0.f; }

  const short* gkh = kws + (size_t)hk * SQ * DH;
  const short* gvh = vtws + (size_t)hk * DH * SQ;

#define STAGE(buf, kb)                                                          \
  {                                                                             \
    const short* gk = gkh + (size_t)(kb)*64 * DH;                               \
    const short* gv = gvh + (size_t)(kb)*64;                                    \
    _Pragma("unroll") for (int i = 0; i < 4; ++i) {                             \
      int j = i * 256 + t;                                                      \
      int lbase = (i * 256 + (t & ~63)) << 4;                                   \
      gload16(gk + (size_t)(j >> 4) * DH + ((j & 15) << 3),                     \
              (char*)Ks[buf] + lbase);                                          \
      gload16(gv + (size_t)(j >> 3) * SQ + ((j & 7) << 3),                      \
              (char*)Vt[buf] + lbase);                                          \
    }                                                                           \
  }

  STAGE(0, 0);
  __syncthreads();

  const int row_base = w * 16;

  for (int kb = 0; kb <= qb; ++kb) {
    const int cur = kb & 1;
    if (kb < qb) STAGE(cur ^ 1, kb + 1);  // prefetch next tile under compute

    // ---- S = Q K^T ----
    f32x4 sc_[4] = {};
#pragma unroll
    for (int kd = 0; kd < 4; ++kd) {
      s16x8 bfr[4];
#pragma unroll
      for (int nt = 0; nt < 4; ++nt) {
        int krow = nt * 16 + lr;
        int slot = (kd * 4 + lk) ^ lr;
        bfr[nt] = *(const s16x8*)(Ks[cur] + krow * 128 + slot * 8);
      }
#pragma unroll
      for (int nt = 0; nt < 4; ++nt)
        mfma16(sc_[nt], qf[kd], bfr[nt]);
    }
    // ---- causal mask (diagonal k-block only) ----
    if (kb == qb) {
#pragma unroll
      for (int nt = 0; nt < 4; ++nt)
#pragma unroll
        for (int r = 0; r < 4; ++r) {
          int col = nt * 16 + lr;
          int row = row_base + lk * 4 + r;
          if (col > row) sc_[nt][r] = -1e30f;
        }
    }
    // ---- online softmax (wave-parallel, 16-lane-group reductions) ----
    {
      f32x4 rm;
#pragma unroll
      for (int r = 0; r < 4; ++r)
        rm[r] = fmaxf(fmaxf(sc_[0][r], sc_[1][r]), fmaxf(sc_[2][r], sc_[3][r]));
#pragma unroll
      for (int off = 1; off < 16; off <<= 1)
#pragma unroll
        for (int r = 0; r < 4; ++r) rm[r] = fmaxf(rm[r], __shfl_xor(rm[r], off, 16));
      f32x4 mn, scl, rs;
#pragma unroll
      for (int r = 0; r < 4; ++r) {
        mn[r] = fmaxf(m_[r], rm[r]);
        scl[r] = __expf(m_[r] - mn[r]);
        rs[r] = 0.f;
      }
#pragma unroll
      for (int nt = 0; nt < 4; ++nt)
#pragma unroll
        for (int r = 0; r < 4; ++r) {
          sc_[nt][r] = __expf(sc_[nt][r] - mn[r]);
          rs[r] += sc_[nt][r];
        }
#pragma unroll
      for (int off = 1; off < 16; off <<= 1)
#pragma unroll
        for (int r = 0; r < 4; ++r) rs[r] += __shfl_xor(rs[r], off, 16);
#pragma unroll
      for (int r = 0; r < 4; ++r) {
        l_[r] = l_[r] * scl[r] + rs[r];
        m_[r] = mn[r];
      }
#pragma unroll
      for (int dt = 0; dt < 8; ++dt)
#pragma unroll
        for (int r = 0; r < 4; ++r) o[dt][r] *= scl[r];
      short* ps = (short*)Ps[w];
#pragma unroll
      for (int nt = 0; nt < 4; ++nt)
#pragma unroll
        for (int r = 0; r < 4; ++r)
          ps[(lk * 4 + r) * 72 + nt * 16 + lr] = f2bf(sc_[nt][r]);
    }
    // ---- O += P V ----
    {
      const short* ps = (const short*)Ps[w];
#pragma unroll
      for (int kp = 0; kp < 2; ++kp) {
        s16x8 pa = *(const s16x8*)(ps + lr * 72 + kp * 32 + lk * 8);
#pragma unroll
        for (int dt = 0; dt < 8; ++dt) {
          int drow = dt * 16 + lr;
          int slot = (kp * 4 + lk) ^ (lr & 7);
          s16x8 vb = *(const s16x8*)(Vt[cur] + drow * 64 + slot * 8);
          mfma16(o[dt], pa, vb);
        }
      }
    }
    __syncthreads();
  }
#undef STAGE

  // ---- epilogue: O /= l, write bf16 [s][h*128+d] linear ----
#pragma unroll
  for (int dt = 0; dt < 8; ++dt) {
    int col = h * DH + dt * 16 + lr;
#pragma unroll
    for (int r = 0; r < 4; ++r) {
      int srow = qb * 64 + w * 16 + lk * 4 + r;
      float val = o[dt][r] / l_[r];
      attnws[(size_t)srow * 2048 + col] = f2bf(val);
    }
  }
}

extern "C" void kernel_launch(void* const* d_in, const int* in_sizes, int n_in,
                              void* d_out, int out_size, void* d_ws, size_t ws_size,
                              hipStream_t stream) {
  (void)in_sizes; (void)n_in; (void)out_size; (void)ws_size;
  const float* x     = (const float*)d_in[0];
  const float* w_qkv = (const float*)d_in[2];
  const float* b_qkv = (const float*)d_in[3];
  const float* w_o   = (const float*)d_in[4];
  const float* b_o   = (const float*)d_in[5];
  const float* pe    = (const float*)d_in[6];
  float* out = (float*)d_out;

  short* xb     = (short*)d_ws;                        // bf16 [2048][2048]
  short* wqkvb  = xb + (size_t)2048 * 2048;            // bf16 [2560][2048]
  short* wob    = wqkvb + (size_t)2560 * 2048;         // bf16 [2048][2048]
  short* qws    = wob + (size_t)2048 * 2048;           // bf16 [16][2048][128]
  short* kws    = qws + (size_t)16 * 2048 * 128;       // bf16 [2][2048][128] swizzled
  short* vtws   = kws + (size_t)2 * 2048 * 128;        // bf16 [2][128][2048] swizzled
  short* attnws = vtws + (size_t)2 * 128 * 2048;       // bf16 [2048][2048]

  cvt_bf16<<<2048, 256, 0, stream>>>(x, xb, 2048 * 2048 / 8);
  cvt_bf16<<<2560, 256, 0, stream>>>(w_qkv, wqkvb, 2560 * 2048 / 8);
  cvt_bf16<<<2048, 256, 0, stream>>>(w_o, wob, 2048 * 2048 / 8);
  gemm_bt_bias<1><<<dim3(2560 / 128, 2048 / 128), 256, 0, stream>>>(
      xb, wqkvb, b_qkv, nullptr, pe, qws, kws, vtws, 2048, 2560, 2048);
  attn_fwd<<<512, 256, 0, stream>>>(qws, kws, vtws, attnws);
  gemm_bt_bias<0><<<dim3(2048 / 128, 2048 / 128), 256, 0, stream>>>(
      attnws, wob, b_o, out, nullptr, nullptr, nullptr, nullptr, 2048, 2048, 2048);
}

// Round 5
// 158.717 us; speedup vs baseline: 1.1937x; 1.1937x over previous
//
#include <hip/hip_runtime.h>
#include <stdint.h>

#define SQ 2048
#define DH 128
#define SCALER 0.08838834764831845f  // 1/sqrt(128)

typedef float f32x4 __attribute__((ext_vector_type(4)));
typedef short s16x8 __attribute__((ext_vector_type(8)));

__device__ __forceinline__ short f2bf(float f) {
  uint32_t x = __float_as_uint(f);
  uint32_t r = (x + 0x7fffu + ((x >> 16) & 1u)) >> 16;  // RNE
  return (short)(r & 0xffffu);
}

__device__ __forceinline__ void mfma16(f32x4& d, s16x8 a, s16x8 b) {
  asm("v_mfma_f32_16x16x32_bf16 %0, %1, %2, %0" : "+v"(d) : "v"(a), "v"(b));
}

__device__ __forceinline__ void gload16(const void* g, void* l) {
  __builtin_amdgcn_global_load_lds(
      (__attribute__((address_space(1))) void*)const_cast<void*>(g),
      (__attribute__((address_space(3))) void*)l, 16, 0, 0);
}

// ---------------- f32 -> bf16 convert, 3 sources, contiguous dst ----------------
__global__ __launch_bounds__(256) void cvt3_bf16(
    const float* __restrict__ a, const float* __restrict__ b,
    const float* __restrict__ c, short* __restrict__ out,
    int na8, int nb8, int nc8) {
  int i = blockIdx.x * 256 + threadIdx.x;
  if (i >= na8 + nb8 + nc8) return;
  const float* src;
  if (i < na8) src = a + (size_t)i * 8;
  else if (i < na8 + nb8) src = b + (size_t)(i - na8) * 8;
  else src = c + (size_t)(i - na8 - nb8) * 8;
  const float4* p = (const float4*)src;
  float4 u = p[0], v = p[1];
  s16x8 o;
  o[0] = f2bf(u.x); o[1] = f2bf(u.y); o[2] = f2bf(u.z); o[3] = f2bf(u.w);
  o[4] = f2bf(v.x); o[5] = f2bf(v.y); o[6] = f2bf(v.z); o[7] = f2bf(v.w);
  *((s16x8*)out + i) = o;
}

// ---------------- GEMM: C[M][N] = A[M][K] * B[N][K]^T + bias ----------------
// Tile 128(M) x 64(N), BK=64, 4 waves (2Mx2N), wave-tile 64x32.
// MODE 0: plain f32 C write.  MODE 1: fused RoPE+split epilogue (QKV proj).
template <int MODE>
__global__ __launch_bounds__(256) void gemm_bt_bias(
    const short* __restrict__ A, const short* __restrict__ B,
    const float* __restrict__ bias, float* __restrict__ C,
    const float* __restrict__ pe, short* __restrict__ qws,
    short* __restrict__ kws, short* __restrict__ vtws,
    int M, int N, int K) {
  __shared__ __align__(16) short smem[128 * 64 + 64 * 64];  // As | Bs (24 KB)
  short* As = smem;             // [128][64]
  short* Bs = smem + 128 * 64;  // [64][64]
  const int t = threadIdx.x;
  const int l = t & 63, w = t >> 6;
  const int wr = w >> 1, wc = w & 1;
  const int lr = l & 15, lk = l >> 4;
  const int m0 = blockIdx.y * 128, n0 = blockIdx.x * 64;

  f32x4 acc[4][2] = {};

  for (int kt = 0; kt < K; kt += 64) {
    const short* ga = A + (size_t)m0 * K + kt;
    const short* gb = B + (size_t)n0 * K + kt;
#pragma unroll
    for (int i = 0; i < 4; ++i) {
      int j = i * 256 + t;                       // A chunk id, 0..1023
      int lbase = (i * 256 + (t & ~63)) << 4;
      gload16(ga + (size_t)(j >> 3) * K + ((j & 7) << 3), (char*)As + lbase);
    }
#pragma unroll
    for (int i = 0; i < 2; ++i) {
      int j = i * 256 + t;                       // B chunk id, 0..511
      int lbase = (i * 256 + (t & ~63)) << 4;
      gload16(gb + (size_t)(j >> 3) * K + ((j & 7) << 3), (char*)Bs + lbase);
    }
    __syncthreads();
#pragma unroll
    for (int ks = 0; ks < 2; ++ks) {
      s16x8 af[4], bg[2];
#pragma unroll
      for (int i = 0; i < 4; ++i)
        af[i] = *(const s16x8*)(As + (wr * 64 + i * 16 + lr) * 64 + ks * 32 + lk * 8);
#pragma unroll
      for (int i = 0; i < 2; ++i)
        bg[i] = *(const s16x8*)(Bs + (wc * 32 + i * 16 + lr) * 64 + ks * 32 + lk * 8);
#pragma unroll
      for (int mi = 0; mi < 4; ++mi)
#pragma unroll
        for (int ni = 0; ni < 2; ++ni)
          mfma16(acc[mi][ni], af[mi], bg[ni]);
    }
    __syncthreads();
  }

  if (MODE == 0) {
#pragma unroll
    for (int mi = 0; mi < 4; ++mi) {
      int row = m0 + wr * 64 + mi * 16 + lk * 4;
#pragma unroll
      for (int ni = 0; ni < 2; ++ni) {
        int col = n0 + wc * 32 + ni * 16 + lr;
        float bv = bias[col];
#pragma unroll
        for (int r = 0; r < 4; ++r)
          C[(size_t)(row + r) * N + col] = acc[mi][ni][r] + bv;
      }
    }
  } else {
    // ---- rope in-register, re-layout through LDS, coalesced stores ----
    if (n0 < 2304) {  // Q or K: Ct s-major [128][72]
      short* Ct = smem;
#pragma unroll
      for (int mi = 0; mi < 4; ++mi) {
        int row_l = wr * 64 + mi * 16 + lk * 4;
#pragma unroll
        for (int ni = 0; ni < 2; ++ni) {
          int col_l = wc * 32 + ni * 16 + lr;
          int col = n0 + col_l;
          float bv = bias[col];
          int d = col & 127;
#pragma unroll
          for (int r = 0; r < 4; ++r) {
            float v = acc[mi][ni][r] + bv;
            float p = __shfl_xor(v, 1);
            int s = m0 + row_l + r;
            const float* per = pe + (size_t)s * 256;
            float y = v * per[d] + p * per[128 + d];
            if (n0 < 2048) y *= SCALER;
            Ct[(row_l + r) * 72 + col_l] = f2bf(y);
          }
        }
      }
      __syncthreads();
      if (n0 < 2048) {  // Q: [hq][s][128] linear
        int hq = n0 >> 7, d0 = n0 & 127;
#pragma unroll
        for (int i = 0; i < 4; ++i) {
          int idx = i * 256 + t;       // 1024 chunks: 128 s x 8 d-chunks
          int sl = idx >> 3, c = idx & 7;
          s16x8 val = *(const s16x8*)(Ct + sl * 72 + c * 8);
          *(s16x8*)(qws + ((size_t)hq * SQ + m0 + sl) * DH + d0 + c * 8) = val;
        }
      } else {          // K: swizzled slots within 128-d row
        int hk = (n0 - 2048) >> 7, d0 = (n0 - 2048) & 127;
#pragma unroll
        for (int i = 0; i < 4; ++i) {
          int idx = i * 256 + t;
          int sl = idx >> 3, c = idx & 7;
          s16x8 val = *(const s16x8*)(Ct + sl * 72 + c * 8);
          int slot = ((d0 >> 3) + c) ^ (sl & 15);
          *(s16x8*)(kws + (size_t)hk * SQ * DH + (size_t)(m0 + sl) * DH + slot * 8) = val;
        }
      }
    } else {  // V: Ct d-major [64][136]
      short* Ct = smem;
      int hk = (n0 - 2304) >> 7, d0 = (n0 - 2304) & 127;
#pragma unroll
      for (int mi = 0; mi < 4; ++mi) {
        int row_l = wr * 64 + mi * 16 + lk * 4;
#pragma unroll
        for (int ni = 0; ni < 2; ++ni) {
          int col_l = wc * 32 + ni * 16 + lr;
          float bv = bias[n0 + col_l];
#pragma unroll
          for (int r = 0; r < 4; ++r)
            Ct[col_l * 136 + row_l + r] = f2bf(acc[mi][ni][r] + bv);
        }
      }
      __syncthreads();
#pragma unroll
      for (int i = 0; i < 4; ++i) {
        int idx = i * 256 + t;         // 1024 chunks: 64 d x 16 s-chunks
        int dl = idx >> 4, c = idx & 15;
        s16x8 val = *(const s16x8*)(Ct + dl * 136 + c * 8);
        int d = d0 + dl;
        size_t dst = (size_t)hk * DH * SQ + (size_t)d * SQ +
                     (size_t)((m0 >> 6) + (c >> 3)) * 64 +
                     (size_t)(((c & 7) ^ (d & 7)) << 3);
        *(s16x8*)(vtws + dst) = val;
      }
    }
  }
}

// ---------------- Flash attention ----------------
// 512 WGs: (h, qb). 4 waves x 16 q-rows (QBLK=64). KBLK=64, double-buffered.
// qb mapping balances co-resident pairs (bx, bx+256): iteration sums == 33.
__global__ __launch_bounds__(256) void attn_fwd(
    const short* __restrict__ qws, const short* __restrict__ kws,
    const short* __restrict__ vtws, short* __restrict__ attnws) {
  __shared__ __align__(16) short Ks[2][64 * 128];  // [buf][krow][d], slots swizzled
  __shared__ __align__(16) short Vt[2][128 * 64];  // [buf][d][kcol], slots swizzled
  __shared__ __align__(16) short Ps[4][16 * 72];   // per-wave P, row pad 72

  const int bx = blockIdx.x;
  const int h = bx & 15;
  const int i_ = bx >> 4;
  const int qb = (i_ < 16) ? (31 - i_) : (i_ - 16);  // balanced pairing
  const int hk = h >> 3;
  const int t = threadIdx.x, l = t & 63, w = t >> 6;
  const int lr = l & 15, lk = l >> 4;

  s16x8 qf[4];
  {
    const short* qbase = qws + ((size_t)h * SQ + (size_t)qb * 64 + w * 16) * DH;
#pragma unroll
    for (int kd = 0; kd < 4; ++kd)
      qf[kd] = *(const s16x8*)(qbase + (size_t)lr * DH + kd * 32 + lk * 8);
  }

  f32x4 o[8] = {};
  f32x4 m_, l_;
#pragma unroll
  for (int r = 0; r < 4; ++r) { m_[r] = -1e30f; l_[r] = 0.f; }

  const short* gkh = kws + (size_t)hk * SQ * DH;
  const short* gvh = vtws + (size_t)hk * DH * SQ;

#define STAGE(buf, kb)                                                          \
  {                                                                             \
    const short* gk = gkh + (size_t)(kb)*64 * DH;                               \
    const short* gv = gvh + (size_t)(kb)*64;                                    \
    _Pragma("unroll") for (int i = 0; i < 4; ++i) {                             \
      int j = i * 256 + t;                                                      \
      int lbase = (i * 256 + (t & ~63)) << 4;                                   \
      gload16(gk + (size_t)(j >> 4) * DH + ((j & 15) << 3),                     \
              (char*)Ks[buf] + lbase);                                          \
      gload16(gv + (size_t)(j >> 3) * SQ + ((j & 7) << 3),                      \
              (char*)Vt[buf] + lbase);                                          \
    }                                                                           \
  }

  STAGE(0, 0);
  __syncthreads();

  const int row_base = w * 16;

  for (int kb = 0; kb <= qb; ++kb) {
    const int cur = kb & 1;
    if (kb < qb) STAGE(cur ^ 1, kb + 1);  // prefetch next tile under compute

    // ---- S = Q K^T ----
    f32x4 sc_[4] = {};
#pragma unroll
    for (int kd = 0; kd < 4; ++kd) {
      s16x8 bfr[4];
#pragma unroll
      for (int nt = 0; nt < 4; ++nt) {
        int krow = nt * 16 + lr;
        int slot = (kd * 4 + lk) ^ lr;
        bfr[nt] = *(const s16x8*)(Ks[cur] + krow * 128 + slot * 8);
      }
#pragma unroll
      for (int nt = 0; nt < 4; ++nt)
        mfma16(sc_[nt], qf[kd], bfr[nt]);
    }
    // ---- causal mask (diagonal k-block only) ----
    if (kb == qb) {
#pragma unroll
      for (int nt = 0; nt < 4; ++nt)
#pragma unroll
        for (int r = 0; r < 4; ++r) {
          int col = nt * 16 + lr;
          int row = row_base + lk * 4 + r;
          if (col > row) sc_[nt][r] = -1e30f;
        }
    }
    // ---- online softmax ----
    {
      f32x4 rm;
#pragma unroll
      for (int r = 0; r < 4; ++r)
        rm[r] = fmaxf(fmaxf(sc_[0][r], sc_[1][r]), fmaxf(sc_[2][r], sc_[3][r]));
#pragma unroll
      for (int off = 1; off < 16; off <<= 1)
#pragma unroll
        for (int r = 0; r < 4; ++r) rm[r] = fmaxf(rm[r], __shfl_xor(rm[r], off, 16));
      f32x4 mn, scl, rs;
#pragma unroll
      for (int r = 0; r < 4; ++r) {
        mn[r] = fmaxf(m_[r], rm[r]);
        scl[r] = __expf(m_[r] - mn[r]);
        rs[r] = 0.f;
      }
#pragma unroll
      for (int nt = 0; nt < 4; ++nt)
#pragma unroll
        for (int r = 0; r < 4; ++r) {
          sc_[nt][r] = __expf(sc_[nt][r] - mn[r]);
          rs[r] += sc_[nt][r];
        }
#pragma unroll
      for (int off = 1; off < 16; off <<= 1)
#pragma unroll
        for (int r = 0; r < 4; ++r) rs[r] += __shfl_xor(rs[r], off, 16);
#pragma unroll
      for (int r = 0; r < 4; ++r) {
        l_[r] = l_[r] * scl[r] + rs[r];
        m_[r] = mn[r];
      }
#pragma unroll
      for (int dt = 0; dt < 8; ++dt)
#pragma unroll
        for (int r = 0; r < 4; ++r) o[dt][r] *= scl[r];
      short* ps = (short*)Ps[w];
#pragma unroll
      for (int nt = 0; nt < 4; ++nt)
#pragma unroll
        for (int r = 0; r < 4; ++r)
          ps[(lk * 4 + r) * 72 + nt * 16 + lr] = f2bf(sc_[nt][r]);
    }
    // ---- O += P V ----
    {
      const short* ps = (const short*)Ps[w];
#pragma unroll
      for (int kp = 0; kp < 2; ++kp) {
        s16x8 pa = *(const s16x8*)(ps + lr * 72 + kp * 32 + lk * 8);
#pragma unroll
        for (int dt = 0; dt < 8; ++dt) {
          int drow = dt * 16 + lr;
          int slot = (kp * 4 + lk) ^ (lr & 7);
          s16x8 vb = *(const s16x8*)(Vt[cur] + drow * 64 + slot * 8);
          mfma16(o[dt], pa, vb);
        }
      }
    }
    __syncthreads();
  }
#undef STAGE

  // ---- epilogue ----
#pragma unroll
  for (int dt = 0; dt < 8; ++dt) {
    int col = h * DH + dt * 16 + lr;
#pragma unroll
    for (int r = 0; r < 4; ++r) {
      int srow = qb * 64 + w * 16 + lk * 4 + r;
      float val = o[dt][r] / l_[r];
      attnws[(size_t)srow * 2048 + col] = f2bf(val);
    }
  }
}

extern "C" void kernel_launch(void* const* d_in, const int* in_sizes, int n_in,
                              void* d_out, int out_size, void* d_ws, size_t ws_size,
                              hipStream_t stream) {
  (void)in_sizes; (void)n_in; (void)out_size; (void)ws_size;
  const float* x     = (const float*)d_in[0];
  const float* w_qkv = (const float*)d_in[2];
  const float* b_qkv = (const float*)d_in[3];
  const float* w_o   = (const float*)d_in[4];
  const float* b_o   = (const float*)d_in[5];
  const float* pe    = (const float*)d_in[6];
  float* out = (float*)d_out;

  short* xb     = (short*)d_ws;                        // bf16 [2048][2048]
  short* wqkvb  = xb + (size_t)2048 * 2048;            // bf16 [2560][2048]
  short* wob    = wqkvb + (size_t)2560 * 2048;         // bf16 [2048][2048]
  short* qws    = wob + (size_t)2048 * 2048;           // bf16 [16][2048][128]
  short* kws    = qws + (size_t)16 * 2048 * 128;       // bf16 [2][2048][128] swizzled
  short* vtws   = kws + (size_t)2 * 2048 * 128;        // bf16 [2][128][2048] swizzled
  short* attnws = vtws + (size_t)2 * 128 * 2048;       // bf16 [2048][2048]

  cvt3_bf16<<<6656, 256, 0, stream>>>(x, w_qkv, w_o, xb,
                                      2048 * 2048 / 8, 2560 * 2048 / 8, 2048 * 2048 / 8);
  gemm_bt_bias<1><<<dim3(2560 / 64, 2048 / 128), 256, 0, stream>>>(
      xb, wqkvb, b_qkv, nullptr, pe, qws, kws, vtws, 2048, 2560, 2048);
  attn_fwd<<<512, 256, 0, stream>>>(qws, kws, vtws, attnws);
  gemm_bt_bias<0><<<dim3(2048 / 64, 2048 / 128), 256, 0, stream>>>(
      attnws, wob, b_o, out, nullptr, nullptr, nullptr, nullptr, 2048, 2048, 2048);
}

// Round 8
// 149.618 us; speedup vs baseline: 1.2663x; 1.0608x over previous
//
#include <hip/hip_runtime.h>
#include <stdint.h>

#define SQ 2048
#define DH 128
#define SCALER 0.08838834764831845f  // 1/sqrt(128)

typedef float f32x4 __attribute__((ext_vector_type(4)));
typedef short s16x8 __attribute__((ext_vector_type(8)));
typedef short s16x4 __attribute__((ext_vector_type(4)));

__device__ __forceinline__ short f2bf(float f) {
  uint32_t x = __float_as_uint(f);
  uint32_t r = (x + 0x7fffu + ((x >> 16) & 1u)) >> 16;  // RNE
  return (short)(r & 0xffffu);
}

__device__ __forceinline__ void mfma16(f32x4& d, s16x8 a, s16x8 b) {
  asm("v_mfma_f32_16x16x32_bf16 %0, %1, %2, %0" : "+v"(d) : "v"(a), "v"(b));
}

__device__ __forceinline__ void gload16(const void* g, void* l) {
  __builtin_amdgcn_global_load_lds(
      (__attribute__((address_space(1))) void*)const_cast<void*>(g),
      (__attribute__((address_space(3))) void*)l, 16, 0, 0);
}

// ---------------- f32 -> bf16 convert, 3 sources, contiguous dst ----------------
__global__ __launch_bounds__(256) void cvt3_bf16(
    const float* __restrict__ a, const float* __restrict__ b,
    const float* __restrict__ c, short* __restrict__ out,
    int na8, int nb8, int nc8) {
  int i = blockIdx.x * 256 + threadIdx.x;
  if (i >= na8 + nb8 + nc8) return;
  const float* src;
  if (i < na8) src = a + (size_t)i * 8;
  else if (i < na8 + nb8) src = b + (size_t)(i - na8) * 8;
  else src = c + (size_t)(i - na8 - nb8) * 8;
  const float4* p = (const float4*)src;
  float4 u = p[0], v = p[1];
  s16x8 o;
  o[0] = f2bf(u.x); o[1] = f2bf(u.y); o[2] = f2bf(u.z); o[3] = f2bf(u.w);
  o[4] = f2bf(v.x); o[5] = f2bf(v.y); o[6] = f2bf(v.z); o[7] = f2bf(v.w);
  *((s16x8*)out + i) = o;
}

// ---------------- GEMM: C[M][N] = A[M][K] * B[N][K]^T + bias ----------------
// Tile 128(M) x 64(N), BK=64, 4 waves (2Mx2N), wave-tile 64x32.
// MODE 0: plain f32 C write.  MODE 1: fused RoPE+split epilogue (QKV proj).
template <int MODE>
__global__ __launch_bounds__(256) void gemm_bt_bias(
    const short* __restrict__ A, const short* __restrict__ B,
    const float* __restrict__ bias, float* __restrict__ C,
    const float* __restrict__ pe, short* __restrict__ qws,
    short* __restrict__ kws, short* __restrict__ vtws,
    int M, int N, int K) {
  __shared__ __align__(16) short smem[128 * 64 + 64 * 64];  // As | Bs (24 KB)
  short* As = smem;             // [128][64]
  short* Bs = smem + 128 * 64;  // [64][64]
  const int t = threadIdx.x;
  const int l = t & 63, w = t >> 6;
  const int wr = w >> 1, wc = w & 1;
  const int lr = l & 15, lk = l >> 4;
  const int m0 = blockIdx.y * 128, n0 = blockIdx.x * 64;

  f32x4 acc[4][2] = {};

  for (int kt = 0; kt < K; kt += 64) {
    const short* ga = A + (size_t)m0 * K + kt;
    const short* gb = B + (size_t)n0 * K + kt;
#pragma unroll
    for (int i = 0; i < 4; ++i) {
      int j = i * 256 + t;                       // A chunk id, 0..1023
      int lbase = (i * 256 + (t & ~63)) << 4;
      gload16(ga + (size_t)(j >> 3) * K + ((j & 7) << 3), (char*)As + lbase);
    }
#pragma unroll
    for (int i = 0; i < 2; ++i) {
      int j = i * 256 + t;                       // B chunk id, 0..511
      int lbase = (i * 256 + (t & ~63)) << 4;
      gload16(gb + (size_t)(j >> 3) * K + ((j & 7) << 3), (char*)Bs + lbase);
    }
    __syncthreads();
#pragma unroll
    for (int ks = 0; ks < 2; ++ks) {
      s16x8 af[4], bg[2];
#pragma unroll
      for (int i = 0; i < 4; ++i)
        af[i] = *(const s16x8*)(As + (wr * 64 + i * 16 + lr) * 64 + ks * 32 + lk * 8);
#pragma unroll
      for (int i = 0; i < 2; ++i)
        bg[i] = *(const s16x8*)(Bs + (wc * 32 + i * 16 + lr) * 64 + ks * 32 + lk * 8);
#pragma unroll
      for (int mi = 0; mi < 4; ++mi)
#pragma unroll
        for (int ni = 0; ni < 2; ++ni)
          mfma16(acc[mi][ni], af[mi], bg[ni]);
    }
    __syncthreads();
  }

  if (MODE == 0) {
#pragma unroll
    for (int mi = 0; mi < 4; ++mi) {
      int row = m0 + wr * 64 + mi * 16 + lk * 4;
#pragma unroll
      for (int ni = 0; ni < 2; ++ni) {
        int col = n0 + wc * 32 + ni * 16 + lr;
        float bv = bias[col];
#pragma unroll
        for (int r = 0; r < 4; ++r)
          C[(size_t)(row + r) * N + col] = acc[mi][ni][r] + bv;
      }
    }
  } else {
    // ---- rope in-register, re-layout through LDS, coalesced stores ----
    if (n0 < 2304) {  // Q or K: Ct s-major [128][72]
      short* Ct = smem;
#pragma unroll
      for (int mi = 0; mi < 4; ++mi) {
        int row_l = wr * 64 + mi * 16 + lk * 4;
#pragma unroll
        for (int ni = 0; ni < 2; ++ni) {
          int col_l = wc * 32 + ni * 16 + lr;
          int col = n0 + col_l;
          float bv = bias[col];
          int d = col & 127;
#pragma unroll
          for (int r = 0; r < 4; ++r) {
            float v = acc[mi][ni][r] + bv;
            float p = __shfl_xor(v, 1);
            int s = m0 + row_l + r;
            const float* per = pe + (size_t)s * 256;
            float y = v * per[d] + p * per[128 + d];
            if (n0 < 2048) y *= SCALER;
            Ct[(row_l + r) * 72 + col_l] = f2bf(y);
          }
        }
      }
      __syncthreads();
      if (n0 < 2048) {  // Q: [hq][s][128] linear
        int hq = n0 >> 7, d0 = n0 & 127;
#pragma unroll
        for (int i = 0; i < 4; ++i) {
          int idx = i * 256 + t;       // 1024 chunks: 128 s x 8 d-chunks
          int sl = idx >> 3, c = idx & 7;
          s16x8 val = *(const s16x8*)(Ct + sl * 72 + c * 8);
          *(s16x8*)(qws + ((size_t)hq * SQ + m0 + sl) * DH + d0 + c * 8) = val;
        }
      } else {          // K: swizzled slots within 128-d row (round-5 formula)
        int hk = (n0 - 2048) >> 7, d0 = (n0 - 2048) & 127;
#pragma unroll
        for (int i = 0; i < 4; ++i) {
          int idx = i * 256 + t;
          int sl = idx >> 3, c = idx & 7;
          s16x8 val = *(const s16x8*)(Ct + sl * 72 + c * 8);
          int slot = ((d0 >> 3) + c) ^ (sl & 15);
          *(s16x8*)(kws + (size_t)hk * SQ * DH + (size_t)(m0 + sl) * DH + slot * 8) = val;
        }
      }
    } else {  // V: Ct d-major [64][136]
      short* Ct = smem;
      int hk = (n0 - 2304) >> 7, d0 = (n0 - 2304) & 127;
#pragma unroll
      for (int mi = 0; mi < 4; ++mi) {
        int row_l = wr * 64 + mi * 16 + lk * 4;
#pragma unroll
        for (int ni = 0; ni < 2; ++ni) {
          int col_l = wc * 32 + ni * 16 + lr;
          float bv = bias[n0 + col_l];
#pragma unroll
          for (int r = 0; r < 4; ++r)
            Ct[col_l * 136 + row_l + r] = f2bf(acc[mi][ni][r] + bv);
        }
      }
      __syncthreads();
#pragma unroll
      for (int i = 0; i < 4; ++i) {
        int idx = i * 256 + t;         // 1024 chunks: 64 d x 16 s-chunks
        int dl = idx >> 4, c = idx & 15;
        s16x8 val = *(const s16x8*)(Ct + dl * 136 + c * 8);
        int d = d0 + dl;
        size_t dst = (size_t)hk * DH * SQ + (size_t)d * SQ +
                     (size_t)((m0 >> 6) + (c >> 3)) * 64 +
                     (size_t)(((c & 7) ^ (d & 7)) << 3);
        *(s16x8*)(vtws + dst) = val;
      }
    }
  }
}

// ---------------- Flash attention (swapped QK^T; P via per-wave LDS) ----------------
// BISECT vs round 6: plain K rows (nt*16+lr, round-5 addresses), no bit4 swizzle,
// P re-layout through LDS (round-5-proven), in-lane softmax kept.
__global__ __launch_bounds__(256) void attn_fwd(
    const short* __restrict__ qws, const short* __restrict__ kws,
    const short* __restrict__ vtws, short* __restrict__ attnws) {
  __shared__ __align__(16) short Ks[2][64 * 128];  // [buf][krow][d], slots swizzled
  __shared__ __align__(16) short Vt[2][128 * 64];  // [buf][d][kcol], slots swizzled
  __shared__ __align__(16) short Ps[4][16 * 72];   // per-wave P [q=lr][64k], pad 72

  const int bx = blockIdx.x;
  const int h = bx & 15;
  const int i_ = bx >> 4;
  const int qb = (i_ < 16) ? (31 - i_) : (i_ - 16);  // balanced pairing
  const int hk = h >> 3;
  const int t = threadIdx.x, l = t & 63, w = t >> 6;
  const int lr = l & 15, lk = l >> 4;

  // Q fragments (B-operand of swapped QK^T): lane holds Q[q=lr][d-slice]
  s16x8 qf[4];
  {
    const short* qbase = qws + ((size_t)h * SQ + (size_t)qb * 64 + w * 16) * DH;
#pragma unroll
    for (int kd = 0; kd < 4; ++kd)
      qf[kd] = *(const s16x8*)(qbase + (size_t)lr * DH + kd * 32 + lk * 8);
  }

  f32x4 o[8] = {};
  float m_ = -1e30f, l_ = 0.f;

  const short* gkh = kws + (size_t)hk * SQ * DH;
  const short* gvh = vtws + (size_t)hk * DH * SQ;

#define STAGE(buf, kb)                                                          \
  {                                                                             \
    const short* gk = gkh + (size_t)(kb)*64 * DH;                               \
    const short* gv = gvh + (size_t)(kb)*64;                                    \
    _Pragma("unroll") for (int i = 0; i < 4; ++i) {                             \
      int j = i * 256 + t;                                                      \
      int lbase = (i * 256 + (t & ~63)) << 4;                                   \
      gload16(gk + (size_t)(j >> 4) * DH + ((j & 15) << 3),                     \
              (char*)Ks[buf] + lbase);                                          \
      gload16(gv + (size_t)(j >> 3) * SQ + ((j & 7) << 3),                      \
              (char*)Vt[buf] + lbase);                                          \
    }                                                                           \
  }

  STAGE(0, 0);
  __syncthreads();

  for (int kb = 0; kb <= qb; ++kb) {
    const int cur = kb & 1;
    if (kb < qb) STAGE(cur ^ 1, kb + 1);  // prefetch next tile under compute

    // ---- S^T = K Q^T : lane gets S[q=lr][col = nt*16 + lk*4 + r] ----
    f32x4 sc_[4] = {};
#pragma unroll
    for (int kd = 0; kd < 4; ++kd) {
#pragma unroll
      for (int nt = 0; nt < 4; ++nt) {
        int krow = nt * 16 + lr;
        int slot = (kd * 4 + lk) ^ lr;
        s16x8 kf = *(const s16x8*)(Ks[cur] + krow * 128 + slot * 8);
        mfma16(sc_[nt], kf, qf[kd]);
      }
    }
    // ---- causal mask (diagonal k-block only) ----
    if (kb == qb) {
      int qloc = w * 16 + lr;
#pragma unroll
      for (int nt = 0; nt < 4; ++nt)
#pragma unroll
        for (int r = 0; r < 4; ++r) {
          int col = nt * 16 + lk * 4 + r;
          if (col > qloc) sc_[nt][r] = -1e30f;
        }
    }
    // ---- online softmax: in-lane over 16, then 2 shuffles ----
    {
      float rm = -1e30f;
#pragma unroll
      for (int nt = 0; nt < 4; ++nt)
        rm = fmaxf(rm, fmaxf(fmaxf(sc_[nt][0], sc_[nt][1]),
                             fmaxf(sc_[nt][2], sc_[nt][3])));
      rm = fmaxf(rm, __shfl_xor(rm, 16));
      rm = fmaxf(rm, __shfl_xor(rm, 32));
      float mn = fmaxf(m_, rm);
      float scl = __expf(m_ - mn);
      float rs = 0.f;
#pragma unroll
      for (int nt = 0; nt < 4; ++nt)
#pragma unroll
        for (int r = 0; r < 4; ++r) {
          sc_[nt][r] = __expf(sc_[nt][r] - mn);
          rs += sc_[nt][r];
        }
      rs += __shfl_xor(rs, 16);
      rs += __shfl_xor(rs, 32);
      l_ = l_ * scl + rs;
      m_ = mn;
#pragma unroll
      for (int dt = 0; dt < 8; ++dt)
#pragma unroll
        for (int r = 0; r < 4; ++r) o[dt][r] *= scl;
    }
    // ---- P -> per-wave LDS (row q=lr, col = nt*16 + lk*4 + r) ----
    {
      short* ps = (short*)Ps[w];
#pragma unroll
      for (int nt = 0; nt < 4; ++nt)
#pragma unroll
        for (int r = 0; r < 4; ++r)
          ps[lr * 72 + nt * 16 + lk * 4 + r] = f2bf(sc_[nt][r]);
    }
    // ---- O^T += V^T P^T : A = Vt row-frag, B = P from LDS ----
    {
      const short* ps = (const short*)Ps[w];
#pragma unroll
      for (int kp = 0; kp < 2; ++kp) {
        s16x8 pbf = *(const s16x8*)(ps + lr * 72 + kp * 32 + lk * 8);
#pragma unroll
        for (int dt = 0; dt < 8; ++dt) {
          int drow = dt * 16 + lr;
          int slot = (kp * 4 + lk) ^ (lr & 7);
          s16x8 vb = *(const s16x8*)(Vt[cur] + drow * 64 + slot * 8);
          mfma16(o[dt], vb, pbf);
        }
      }
    }
    __syncthreads();
  }
#undef STAGE

  // ---- epilogue: lane owns q-row lr; o[dt][r] = O[q][d=dt*16+lk*4+r] ----
  {
    int srow = qb * 64 + w * 16 + lr;
#pragma unroll
    for (int dt = 0; dt < 8; ++dt) {
      s16x4 st;
#pragma unroll
      for (int r = 0; r < 4; ++r) st[r] = f2bf(o[dt][r] / l_);
      *(s16x4*)(attnws + (size_t)srow * 2048 + h * DH + dt * 16 + lk * 4) = st;
    }
  }
}

extern "C" void kernel_launch(void* const* d_in, const int* in_sizes, int n_in,
                              void* d_out, int out_size, void* d_ws, size_t ws_size,
                              hipStream_t stream) {
  (void)in_sizes; (void)n_in; (void)out_size; (void)ws_size;
  const float* x     = (const float*)d_in[0];
  const float* w_qkv = (const float*)d_in[2];
  const float* b_qkv = (const float*)d_in[3];
  const float* w_o   = (const float*)d_in[4];
  const float* b_o   = (const float*)d_in[5];
  const float* pe    = (const float*)d_in[6];
  float* out = (float*)d_out;

  short* xb     = (short*)d_ws;                        // bf16 [2048][2048]
  short* wqkvb  = xb + (size_t)2048 * 2048;            // bf16 [2560][2048]
  short* wob    = wqkvb + (size_t)2560 * 2048;         // bf16 [2048][2048]
  short* qws    = wob + (size_t)2048 * 2048;           // bf16 [16][2048][128]
  short* kws    = qws + (size_t)16 * 2048 * 128;       // bf16 [2][2048][128] swizzled
  short* vtws   = kws + (size_t)2 * 2048 * 128;        // bf16 [2][128][2048] swizzled
  short* attnws = vtws + (size_t)2 * 128 * 2048;       // bf16 [2048][2048]

  cvt3_bf16<<<6656, 256, 0, stream>>>(x, w_qkv, w_o, xb,
                                      2048 * 2048 / 8, 2560 * 2048 / 8, 2048 * 2048 / 8);
  gemm_bt_bias<1><<<dim3(2560 / 64, 2048 / 128), 256, 0, stream>>>(
      xb, wqkvb, b_qkv, nullptr, pe, qws, kws, vtws, 2048, 2560, 2048);
  attn_fwd<<<512, 256, 0, stream>>>(qws, kws, vtws, attnws);
  gemm_bt_bias<0><<<dim3(2048 / 64, 2048 / 128), 256, 0, stream>>>(
      attnws, wob, b_o, out, nullptr, nullptr, nullptr, nullptr, 2048, 2048, 2048);
}